// Round 5
// baseline (237.140 us; speedup 1.0000x reference)
//
#include <hip/hip_runtime.h>
#include <hip/hip_bf16.h>
#include <cmath>

typedef float f32x16 __attribute__((ext_vector_type(16)));
typedef __bf16 bf16x8 __attribute__((ext_vector_type(8)));
typedef __bf16 bf16x4 __attribute__((ext_vector_type(4)));

#define NE 8
#define H 1024
#define DF 2048
#define WCOLS 16384
#define NTOK 4096
#define MROWS 8192
#define NBLK 64
#define TILE_E 4096          // elements per (128 x 32) bf16 tile

typedef const __attribute__((address_space(1))) unsigned int glb_u32;
typedef __attribute__((address_space(3))) unsigned int lds_u32;

__device__ __forceinline__ void async_load16(const void* g, void* l) {
    __builtin_amdgcn_global_load_lds((glb_u32*)g, (lds_u32*)l, 16, 0, 0);
}

// ---- prep: blocks [0,1024) = router (+ x->bf16, last block also sorts),
//            blocks [1024,9216) = w1 transpose into chunk-major tiled Wt ----
__global__ __launch_bounds__(256) void prep_kernel(
    const float* __restrict__ x, const float* __restrict__ rw,
    const float* __restrict__ w1,
    float* __restrict__ logits, int* __restrict__ sel, float* __restrict__ rwn,
    __bf16* __restrict__ xb, __bf16* __restrict__ Wt,
    int* __restrict__ ctr,
    int* __restrict__ stok, float* __restrict__ srw, int* __restrict__ bexp)
{
    int b = blockIdx.x;
    int tid = threadIdx.x;
    if (b >= 1024) {
        // ---- transpose: Wt el = (c*32+kb)*4096 + g4*1024 + ch*256 + r32*8 + j
        //      = w1[kb*32 + ch*8 + j][c*128 + g4*32 + r32]
        int gblk = b - 1024;           // 0..8191
        int pair = gblk >> 1;          // c*32 + kb
        int c  = pair >> 5;
        int kb = pair & 31;
        int g4 = (gblk & 1) * 2 + (tid >> 7);
        int ch = (tid >> 5) & 3;
        int r32 = tid & 31;
        const float* src = w1 + (size_t)(kb * 32 + ch * 8) * WCOLS + c * 128 + g4 * 32 + r32;
        bf16x8 o;
#pragma unroll
        for (int j = 0; j < 8; ++j) o[j] = (__bf16)src[(size_t)j * WCOLS];
        *(bf16x8*)(Wt + (size_t)pair * TILE_E + g4 * 1024 + ch * 256 + r32 * 8) = o;
        return;
    }
    // ---------------- router: 1 token per wave ----------------
    {
        int tok  = b * 4 + (tid >> 6);
        int lane = tid & 63;
        const float* xr = x + (size_t)tok * H;
        __bf16* xbr = xb + (size_t)tok * H;
        float acc[NE];
#pragma unroll
        for (int e = 0; e < NE; ++e) acc[e] = 0.f;
#pragma unroll
        for (int it = 0; it < 4; ++it) {
            int k = (it * 64 + lane) * 4;
            float4 xv = *(const float4*)(xr + k);
            bf16x4 xc;
            xc[0] = (__bf16)xv.x; xc[1] = (__bf16)xv.y;
            xc[2] = (__bf16)xv.z; xc[3] = (__bf16)xv.w;
            *(bf16x4*)(xbr + k) = xc;
#pragma unroll
            for (int e = 0; e < NE; ++e) {
                float4 wv = *(const float4*)(rw + e * H + k);
                acc[e] += xv.x * wv.x + xv.y * wv.y + xv.z * wv.z + xv.w * wv.w;
            }
        }
#pragma unroll
        for (int e = 0; e < NE; ++e) {
            float v = acc[e];
#pragma unroll
            for (int off = 32; off > 0; off >>= 1) v += __shfl_xor(v, off, 64);
            acc[e] = v;
        }
        if (lane == 0) {
#pragma unroll
            for (int e = 0; e < NE; ++e) logits[tok * NE + e] = acc[e];
            int i1 = 0; float m1 = acc[0];
#pragma unroll
            for (int e = 1; e < NE; ++e) if (acc[e] > m1) { m1 = acc[e]; i1 = e; }
            int i2 = -1; float m2 = -INFINITY;
#pragma unroll
            for (int e = 0; e < NE; ++e) if (e != i1 && acc[e] > m2) { m2 = acc[e]; i2 = e; }
            float e2 = expf(m2 - m1);
            float inv = 1.f / (1.f + e2);
            sel[tok * 2]     = i1;  sel[tok * 2 + 1] = i2;
            rwn[tok * 2]     = inv; rwn[tok * 2 + 1] = e2 * inv;
        }
    }
    // ---------------- last router block performs the sort ----------------
    __shared__ int lastFlag;
    __syncthreads();
    if (tid == 0) {
        __threadfence();
        int old = atomicAdd(ctr, 1);
        lastFlag = (old == 1023) ? 1 : 0;
    }
    __syncthreads();
    if (!lastFlag) return;
    __threadfence();    // acquire: all router blocks' sel/rwn visible

    __shared__ int cnt[NE][256];
    __shared__ int tot[NE];
    __shared__ int ebase[NE + 1];
    int t = tid;
    int selv[32];
    int lc[NE];
#pragma unroll
    for (int e = 0; e < NE; ++e) lc[e] = 0;
    int base = t * 32;
    for (int j = 0; j < 32; ++j) { selv[j] = sel[base + j]; lc[selv[j]]++; }
#pragma unroll
    for (int e = 0; e < NE; ++e) cnt[e][t] = lc[e];
    __syncthreads();
    {   // parallel exclusive scan: expert g scanned by 32 threads (j = t&31)
        int gg = t >> 5, j = t & 31;
        int s = 0, pre[8];
#pragma unroll
        for (int i = 0; i < 8; ++i) { pre[i] = s; s += cnt[gg][j * 8 + i]; }
        int inc = s;
#pragma unroll
        for (int d = 1; d < 32; d <<= 1) {
            int v = __shfl_up(inc, d, 64);
            if (j >= d) inc += v;
        }
        int excl = inc - s;
#pragma unroll
        for (int i = 0; i < 8; ++i) cnt[gg][j * 8 + i] = excl + pre[i];
        if (j == 31) tot[gg] = inc;
    }
    __syncthreads();
    if (t == 0) {
        int s = 0;
        for (int e = 0; e < NE; ++e) { ebase[e] = s; s += tot[e]; }
        ebase[NE] = s;
    }
    __syncthreads();
    int off[NE];
#pragma unroll
    for (int e = 0; e < NE; ++e) off[e] = ebase[e] + cnt[e][t];
    for (int j = 0; j < 32; ++j) {
        int i = base + j;
        int e = selv[j];
        int pos = off[e]++;
        stok[pos] = i >> 1;
        srw[pos]  = rwn[i];
    }
    __syncthreads();
    if (t < NBLK) {
        int r = t * 128;
        int e = 0;
        while (e < NE - 1 && r >= ebase[e + 1]) ++e;
        bexp[t] = e;
    }
}

// ------------- Block GEMM: chunk-major LDS, fused A-gather, dbuf ------------
// LDS layouts (per 128x32 tile buffer, 4096 elems):
//   A: group g(32 rows)=wave g: [g*1024 .. +1024): sub(16 rows)*512 + ch*128 + r16*8 + j
//      holds A[m=g*32+sub*16+r16][k=ch*8+j]
//   B: group g: [g*1024 .. +1024): ch*256 + r32*8 + j  holds B[n=g*32+r32][k=ch*8+j]
// Both give fragment-read bank pattern = 8 lanes/bank-quad = 8-phase minimum.
__global__ __launch_bounds__(256, 4) void moe_gemm(
    const __bf16* __restrict__ xb, const __bf16* __restrict__ Wt,
    const int* __restrict__ stok, const float* __restrict__ srw,
    const int* __restrict__ bexp, float* __restrict__ out)
{
    __shared__ __align__(16) __bf16 As[2][4096];
    __shared__ __align__(16) __bf16 Bs[2][4096];
    __shared__ int   tokS[128];
    __shared__ float rwS[128];

    int g = blockIdx.x;
    int by = (g & 7) * 8 + ((g >> 3) & 7);   // XCD swizzle
    int bx = g >> 6;
    int tid = threadIdx.x;
    if (tid < 128) {
        tokS[tid] = stok[by * 128 + tid];
        rwS[tid]  = srw[by * 128 + tid];
    }
    int e = bexp[by];
    __syncthreads();

    int lane = tid & 63;
    int wv   = tid >> 6;
    int r16  = lane & 15;              // A staging: row within 16-sub
    int ch4  = lane >> 4;              // A staging: k-chunk 0..3
    const __bf16* aS0 = xb + (size_t)tokS[wv * 32 + r16] * H + ch4 * 8;
    const __bf16* aS1 = xb + (size_t)tokS[wv * 32 + 16 + r16] * H + ch4 * 8;
    const __bf16* bT  = Wt + (size_t)(e * 16 + bx) * 32 * TILE_E + wv * 1024 + lane * 8;

    int l32 = lane & 31;
    int hi  = lane >> 5;
    int rgA0 = (wv & 1) * 2;
    int rgB0 = (wv >> 1) * 2;
    int aoff = (l32 >> 4) * 512 + hi * 128 + (l32 & 15) * 8;
    int boff = hi * 256 + l32 * 8;
    int wm = (wv & 1) * 64;
    int wn = (wv >> 1) * 64;

    f32x16 acc[2][2];
#pragma unroll
    for (int i = 0; i < 2; ++i)
#pragma unroll
        for (int j = 0; j < 2; ++j)
#pragma unroll
            for (int r = 0; r < 16; ++r) acc[i][j][r] = 0.f;

    // prologue: stage kb=0 into buffer 0
    async_load16(aS0, &As[0][wv * 1024]);
    async_load16(aS1, &As[0][wv * 1024 + 512]);
    async_load16(bT,  &Bs[0][wv * 1024]);
    async_load16(bT + 512, &Bs[0][wv * 1024 + 512]);

    for (int kb = 0; kb < 32; ++kb) {
        int cur = kb & 1;
        __syncthreads();               // drains own stage(kb); barrier
        if (kb < 31) {
            const __bf16* aN0 = aS0 + (kb + 1) * 32;
            const __bf16* aN1 = aS1 + (kb + 1) * 32;
            const __bf16* bN  = bT + (size_t)(kb + 1) * TILE_E;
            async_load16(aN0, &As[1 - cur][wv * 1024]);
            async_load16(aN1, &As[1 - cur][wv * 1024 + 512]);
            async_load16(bN,  &Bs[1 - cur][wv * 1024]);
            async_load16(bN + 512, &Bs[1 - cur][wv * 1024 + 512]);
        }
        bf16x8 af[2][2], bfr[2][2];
#pragma unroll
        for (int h = 0; h < 2; ++h) {
#pragma unroll
            for (int ti = 0; ti < 2; ++ti)
                af[ti][h] = *(const bf16x8*)&As[cur][(rgA0 + ti) * 1024 + h * 256 + aoff];
#pragma unroll
            for (int tj = 0; tj < 2; ++tj)
                bfr[tj][h] = *(const bf16x8*)&Bs[cur][(rgB0 + tj) * 1024 + h * 512 + boff];
        }
#pragma unroll
        for (int h = 0; h < 2; ++h)
#pragma unroll
            for (int ti = 0; ti < 2; ++ti)
#pragma unroll
                for (int tj = 0; tj < 2; ++tj)
                    acc[ti][tj] = __builtin_amdgcn_mfma_f32_32x32x16_bf16(
                        af[ti][h], bfr[tj][h], acc[ti][tj], 0, 0, 0);
    }

    // epilogue: gelu (tanh form) * rw; C/D: row=(reg&3)+8*(reg>>2)+4*(lane>>5)
    int rowh = hi * 4;
#pragma unroll
    for (int ti = 0; ti < 2; ++ti)
#pragma unroll
        for (int tj = 0; tj < 2; ++tj)
#pragma unroll
            for (int reg = 0; reg < 16; ++reg) {
                int row = (reg & 3) + 8 * (reg >> 2) + rowh;
                int m = wm + ti * 32 + row;
                int n = wn + tj * 32 + l32;
                float val = acc[ti][tj][reg];
                float u = 0.7978845608028654f * val * (1.f + 0.044715f * val * val);
                float t = __expf(-2.f * fabsf(u));
                float th = (1.f - t) / (1.f + t);
                th = u < 0.f ? -th : th;
                float gv = 0.5f * val * (1.f + th) * rwS[m];
                out[(size_t)(by * 128 + m) * DF + bx * 128 + n] = gv;
            }
}

extern "C" void kernel_launch(void* const* d_in, const int* in_sizes, int n_in,
                              void* d_out, int out_size, void* d_ws, size_t ws_size,
                              hipStream_t stream) {
    (void)in_sizes; (void)n_in; (void)out_size; (void)ws_size;
    const float* x        = (const float*)d_in[0];
    const float* router_w = (const float*)d_in[1];
    const float* w1       = (const float*)d_in[2];
    float* out    = (float*)d_out;
    float* logits = out + (size_t)MROWS * DF;

    char* ws    = (char*)d_ws;
    int*   sel  = (int*)(ws);
    float* rwn  = (float*)(ws + 0x8000);
    int*   stok = (int*)(ws + 0x10000);
    float* srw  = (float*)(ws + 0x18000);
    int*   bexp = (int*)(ws + 0x20000);
    int*   ctr  = (int*)(ws + 0x21000);
    __bf16* xb  = (__bf16*)(ws + (1 << 20));             // 8 MB
    __bf16* Wt  = (__bf16*)(ws + (1 << 20) + (8 << 20)); // 32 MB

    hipMemsetAsync(ctr, 0, 4, stream);
    prep_kernel<<<9216, 256, 0, stream>>>(x, router_w, w1, logits, sel, rwn,
                                          xb, Wt, ctr, stok, srw, bexp);
    moe_gemm<<<16 * NBLK, 256, 0, stream>>>(xb, Wt, stok, srw, bexp, out);
}